// Round 1
// baseline (373.092 us; speedup 1.0000x reference)
//
#include <hip/hip_runtime.h>
#include <math.h>

// R5: transposed ArmInt — zero LDS, zero DS ops.
//
// Evidence from R4 profile: top-5 dispatches are all harness 1-GiB poison
// fills (~160us each, 6.7 TB/s). armint_mfma <= 162us; timed graph ~= 2 fills
// (~320us) + prep + mfma. Controllable slice = mfma's gap to its 44.5us
// memory floor (268MB x-read + 25MB out-write).
//
// R5 removes the whole LDS C->A transform structure by transposing the net:
//   layer0:  D0^T = W0' . X^T      (A = weight frag, B = x frag — the per-lane
//            data both operands need is IDENTICAL to what R4 already loaded;
//            only the MFMA argument order changes)
//   C->B transform: D layout (lane holds 4 rows of col lm) -> B layout (lane
//            holds 8 k-elems of col lm) is a pure redistribution across the 4
//            lanes sharing lm:  per reg r,
//              v_permlane32_swap_b32(X0[r], X1[r])   ; halves
//              v_permlane16_swap_b32(X0[r], X1[r])   ; rows
//            => X0[r] = h[8*quad + r], X1[r] = h[8*quad + 4 + r]  (B-frag!)
//   layer1:  D1^T = W1s . H0,  same trick.
//   output:  only 2 live rows -> f32 VALU dot (exact: all values integers
//            < 2^24) + 2-stage permlane quad-reduce. Kills 4 MFMAs AND the
//            16-elem 2-chunk split of the old output path.
//
// Numerics: identical product set / chunk order to the passing R4 kernel
// (w0hi{a0,a1,a2} + w0lo{a0,a1}; a2*w0lo dropped as before). Output layer is
// now exact f32 integer arithmetic (fewer approximations than R4's bf16 wof).

typedef __attribute__((ext_vector_type(8))) short bf16x8;
typedef __attribute__((ext_vector_type(4))) float f32x4;

#define MFMA16(A, B, C) __builtin_amdgcn_mfma_f32_16x16x32_bf16((A), (B), (C), 0, 0, 0)

__device__ inline short bf_top(float v) {              // top bf16 chunk (bit-trunc)
    return (short)(__float_as_uint(v) >> 16);
}
__device__ inline float bf_topf(float v) {             // same chunk as fp32
    return __uint_as_float(__float_as_uint(v) & 0xffff0000u);
}

// gfx950 lane-swap primitives (both operands updated):
//   permlane32: vdst[32+i] <-> vsrc[i]
//   permlane16: vdst row1 <-> vsrc row0, vdst row3 <-> vsrc row2 (rows = 16 lanes)
__device__ inline void pl32swap(float& a, float& b) {
    asm("v_permlane32_swap_b32 %0, %1" : "+v"(a), "+v"(b));
}
__device__ inline void pl16swap(float& a, float& b) {
    asm("v_permlane16_swap_b32 %0, %1" : "+v"(a), "+v"(b));
}

// d_ws layout:
//   shorts: [0)    w0' hi[32][32]   [1024) w0' lo
//           [2048) w1s hi           [3072) w1s lo
//   floats at byte 8192: bs0[32], bs1[32]

__global__ void armint_prep(const float* __restrict__ w0, const float* __restrict__ b0,
                            const float* __restrict__ w1, const float* __restrict__ b1,
                            short* __restrict__ ws, float* __restrict__ bsf)
{
    int t = threadIdx.x;
    for (int i = t; i < 1024; i += 256) {
        int n = i >> 5, k = i & 31;
        float diag = (n == k) ? 256.0f : 0.0f;

        float a = w0[i] + diag;                       // W0' (unscaled)
        float ahi = bf_topf(a);
        ws[i]          = bf_top(a);
        ws[1024 + i]   = bf_top(a - ahi);             // exact int residue

        float b = (w1[i] + diag) * (1.0f / 256.0f);   // W1s (scaled, exact pow2)
        float bhi = bf_topf(b);
        ws[2048 + i]   = bf_top(b);
        ws[3072 + i]   = bf_top(b - bhi);
    }
    if (t < 32) {
        bsf[t]      = (b0[t] + 128.0f) * (1.0f / 256.0f);
        bsf[32 + t] = (b1[t] + 128.0f) * (1.0f / 256.0f);
    }
}

__global__ __launch_bounds__(256)
void armint_mfma(const float* __restrict__ x, const short* __restrict__ ws,
                 const float* __restrict__ bias, const float* __restrict__ wo,
                 const float* __restrict__ bo, float* __restrict__ out, int nrows)
{
    const int lane = threadIdx.x & 63;
    const int wave = threadIdx.x >> 6;
    const int lm   = lane & 15;
    const int quad = lane >> 4;

    const size_t nn = (size_t)nrows;
    const size_t rowbase = (size_t)blockIdx.x * 128 + (size_t)wave * 32;

    // ---- weight A-fragments: lane holds W[m = lm + 16*hh][k = quad*8 + j] ----
    bf16x8 w0hi[2], w0lo[2], w1hi[2], w1lo[2];
    #pragma unroll
    for (int hh = 0; hh < 2; ++hh) {
        const int o = (lm + 16 * hh) * 32 + quad * 8;
        w0hi[hh] = *(const bf16x8*)(ws + o);
        w0lo[hh] = *(const bf16x8*)(ws + 1024 + o);
        w1hi[hh] = *(const bf16x8*)(ws + 2048 + o);
        w1lo[hh] = *(const bf16x8*)(ws + 3072 + o);
    }
    // per-ROW bias init (transposed D: row = feature 16*hh + 4*quad + r)
    f32x4 bv0[2], bv1[2];
    #pragma unroll
    for (int hh = 0; hh < 2; ++hh) {
        float4 t0 = *(const float4*)(bias + hh * 16 + quad * 4);
        float4 t1 = *(const float4*)(bias + 32 + hh * 16 + quad * 4);
        bv0[hh][0] = t0.x; bv0[hh][1] = t0.y; bv0[hh][2] = t0.z; bv0[hh][3] = t0.w;
        bv1[hh][0] = t1.x; bv1[hh][1] = t1.y; bv1[hh][2] = t1.z; bv1[hh][3] = t1.w;
    }

    // ---- load x as B-fragment (row = t*16+lm, k = quad*8+j), exact 3-chunk split ----
    bf16x8 a0[2], a1[2], a2[2];
    #pragma unroll
    for (int t = 0; t < 2; ++t) {
        const float* xp = x + (rowbase + (size_t)(t * 16 + lm)) * 32 + quad * 8;
        float4 v0 = *(const float4*)xp;
        float4 v1 = *(const float4*)(xp + 4);
        float h[8] = {v0.x, v0.y, v0.z, v0.w, v1.x, v1.y, v1.z, v1.w};
        #pragma unroll
        for (int j = 0; j < 8; ++j) {
            float c0 = bf_topf(h[j]);
            a0[t][j] = bf_top(h[j]);
            float r1 = h[j] - c0;                 // exact
            float c1 = bf_topf(r1);
            a1[t][j] = bf_top(r1);
            a2[t][j] = bf_top(r1 - c1);           // exact, fits one bf16
        }
    }

    // ---- layer 0 (transposed): acc[t][hh] = W0'[16hh..+15][:] . X^T + b ----
    f32x4 acc[2][2];
    #pragma unroll
    for (int t = 0; t < 2; ++t)
        #pragma unroll
        for (int hh = 0; hh < 2; ++hh) {
            f32x4 c = bv0[hh];
            c = MFMA16(w0hi[hh], a0[t], c);
            c = MFMA16(w0hi[hh], a1[t], c);
            c = MFMA16(w0hi[hh], a2[t], c);
            c = MFMA16(w0lo[hh], a0[t], c);
            c = MFMA16(w0lo[hh], a1[t], c);       // a2*w0lo dropped (negligible)
            acc[t][hh] = c;
        }

    // ---- relu/trunc + register-only quad redistribution -> layer-1 B frags ----
    bf16x8 c0f[2], c1f[2];
    #pragma unroll
    for (int t = 0; t < 2; ++t) {
        float X0[4], X1[4];
        #pragma unroll
        for (int r = 0; r < 4; ++r) {
            X0[r] = fmaxf(truncf(acc[t][0][r]), 0.0f);
            X1[r] = fmaxf(truncf(acc[t][1][r]), 0.0f);
            pl32swap(X0[r], X1[r]);
            pl16swap(X0[r], X1[r]);
            // now X0[r] = h0[8*quad + r], X1[r] = h0[8*quad + 4 + r]
        }
        #pragma unroll
        for (int j = 0; j < 8; ++j) {
            float v = (j < 4) ? X0[j] : X1[j - 4];
            float hi = bf_topf(v);
            c0f[t][j] = bf_top(v);
            c1f[t][j] = bf_top(v - hi);           // exact int residue < 256
        }
    }

    // ---- layer 1 (transposed) ----
    #pragma unroll
    for (int t = 0; t < 2; ++t)
        #pragma unroll
        for (int hh = 0; hh < 2; ++hh) {
            f32x4 c = bv1[hh];
            c = MFMA16(w1hi[hh], c0f[t], c);
            c = MFMA16(w1hi[hh], c1f[t], c);
            c = MFMA16(w1lo[hh], c0f[t], c);
            c = MFMA16(w1lo[hh], c1f[t], c);
            acc[t][hh] = c;
        }

    // ---- output layer: exact f32 dot (2 live rows) + permlane quad-reduce ----
    float wlo[2][4], whi[2][4];
    #pragma unroll
    for (int o = 0; o < 2; ++o) {
        float4 va = *(const float4*)(wo + o * 32 + quad * 4);
        float4 vb = *(const float4*)(wo + o * 32 + 16 + quad * 4);
        wlo[o][0] = va.x; wlo[o][1] = va.y; wlo[o][2] = va.z; wlo[o][3] = va.w;
        whi[o][0] = vb.x; whi[o][1] = vb.y; whi[o][2] = vb.z; whi[o][3] = vb.w;
    }
    const float bo0 = bo[0], bo1 = bo[1];

    #pragma unroll
    for (int t = 0; t < 2; ++t) {
        // lane holds h1[4q+r] (hh=0) and h1[16+4q+r] (hh=1) for batch lm
        float p0 = 0.0f, p1 = 0.0f;
        #pragma unroll
        for (int r = 0; r < 4; ++r) {
            float g0 = fmaxf(truncf(acc[t][0][r]), 0.0f);
            float g1 = fmaxf(truncf(acc[t][1][r]), 0.0f);
            p0 += g0 * wlo[0][r] + g1 * whi[0][r];
            p1 += g0 * wlo[1][r] + g1 * whi[1][r];
        }
        // sum across the 4 lanes sharing lm (quads): 32-swap stage, 16-swap stage
        float u0 = p0, u1 = p1;
        pl32swap(p0, u0); p0 += u0;
        pl32swap(p1, u1); p1 += u1;
        float v0 = p0, v1 = p1;
        pl16swap(p0, v0); p0 += v0;
        pl16swap(p1, v1); p1 += v1;

        if (quad == 0) {                          // 16 lanes, coalesced 64B stores
            const size_t row = rowbase + (size_t)(t * 16 + lm);
            float amu = (p0 + bo0) * (1.0f / 256.0f);
            float omu = truncf(amu + copysignf(0.5f, amu)) * (1.0f / 256.0f);
            float als = (p1 + bo1) * (1.0f / 256.0f);
            float ols = truncf(als + copysignf(0.5f, als)) * (1.0f / 256.0f);
            float sc  = expf(fminf(fmaxf(ols - 4.0f, -4.6f), 5.0f));
            out[row]          = omu;
            out[nn + row]     = sc;
            out[2 * nn + row] = ols;
        }
    }
}

extern "C" void kernel_launch(void* const* d_in, const int* in_sizes, int n_in,
                              void* d_out, int out_size, void* d_ws, size_t ws_size,
                              hipStream_t stream) {
    const float* x  = (const float*)d_in[0];
    const float* w0 = (const float*)d_in[1];
    const float* b0 = (const float*)d_in[2];
    const float* w1 = (const float*)d_in[3];
    const float* b1 = (const float*)d_in[4];
    const float* wo = (const float*)d_in[5];
    const float* bo = (const float*)d_in[6];
    float* out = (float*)d_out;

    short* ws  = (short*)d_ws;
    float* bsf = (float*)((char*)d_ws + 8192);

    int nrows = in_sizes[0] / 32;             // B = 2097152, multiple of 128
    int grid = nrows / 128;                   // 128 rows per 256-thread block

    armint_prep<<<1, 256, 0, stream>>>(w0, b0, w1, b1, ws, bsf);
    armint_mfma<<<grid, 256, 0, stream>>>(x, ws, bsf, wo, bo, out, nrows);
}